// Round 4
// baseline (274.598 us; speedup 1.0000x reference)
//
#include <hip/hip_runtime.h>
#include <hip/hip_bf16.h>
#include <stdint.h>

#define DIN 128
#define DHID 128
#define DOUT2 64

// fp32 -> bf16 (round to nearest even), as raw ushort
__device__ __forceinline__ unsigned short f2bf(float f) {
    unsigned u = __float_as_uint(f);
    u += 0x7fffu + ((u >> 16) & 1u);
    return (unsigned short)(u >> 16);
}
__device__ __forceinline__ float bf2f(unsigned short b) {
    return __uint_as_float(((unsigned)b) << 16);
}
__device__ __forceinline__ float bflo(unsigned v) { return __uint_as_float(v << 16); }
__device__ __forceinline__ float bfhi(unsigned v) { return __uint_as_float(v & 0xffff0000u); }

// ---------------- dtype detector (int32 vs int64 edge_index) ----------------
__global__ void detect_i64_kernel(const unsigned* ei, int* flag) {
    int t = threadIdx.x;
    unsigned hi = ei[2 * t + 1];
    unsigned long long vote = __ballot(hi == 0u);
    if (t == 0) *flag = (vote == ~0ull) ? 1 : 0;
}

// ---------------- degree count (dst side, excluding self loops) ----------------
__global__ void deg_count_kernel(const int* ei32, const long long* ei64, const int* flag,
                                 unsigned* deg, int E) {
    int e = blockIdx.x * blockDim.x + threadIdx.x;
    if (e >= E) return;
    int mode = *flag;
    int d = mode ? (int)ei64[(size_t)E + e] : ei32[(size_t)E + e];
    atomicAdd(&deg[d], 1u);
}

// ---------------- dinv = 1/sqrt(deg+1)  (self loop adds 1) ----------------
__global__ void dinv_kernel(const unsigned* deg, float* dinv, int N) {
    int i = blockIdx.x * blockDim.x + threadIdx.x;
    if (i < N) dinv[i] = 1.0f / sqrtf((float)(deg[i] + 1u));
}

// ---------------- hierarchical exclusive scan: deg -> row_ptr, cursor ----------------
__global__ __launch_bounds__(256) void scan_blocksum_kernel(const unsigned* deg, int* bsum,
                                                            int N) {
    __shared__ int s[256];
    int t = threadIdx.x;
    int base = blockIdx.x * 1024 + t * 4;
    int sum = 0;
    if (base + 3 < N) {
        int4 v = *(const int4*)((const int*)deg + base);
        sum = v.x + v.y + v.z + v.w;
    } else {
        for (int j = 0; j < 4; j++)
            if (base + j < N) sum += (int)deg[base + j];
    }
    s[t] = sum;
    __syncthreads();
    for (int off = 128; off > 0; off >>= 1) {
        if (t < off) s[t] += s[t + off];
        __syncthreads();
    }
    if (t == 0) bsum[blockIdx.x] = s[0];
}

__global__ __launch_bounds__(256) void scan_bsum_kernel(int* bsum, int* row_ptr, int nb, int N) {
    __shared__ int s[256];
    int t = threadIdx.x;
    int v = (t < nb) ? bsum[t] : 0;
    s[t] = v;
    __syncthreads();
    for (int off = 1; off < 256; off <<= 1) {
        int u = (t >= off) ? s[t - off] : 0;
        __syncthreads();
        s[t] += u;
        __syncthreads();
    }
    if (t < nb) bsum[t] = s[t] - v;  // exclusive
    if (t == 255) row_ptr[N] = s[255];
}

__global__ __launch_bounds__(256) void scan_write_kernel(const unsigned* deg, const int* bsum,
                                                         int* row_ptr, int* cursor, int N) {
    __shared__ int s[256];
    int t = threadIdx.x;
    int base = blockIdx.x * 1024 + t * 4;
    int d[4];
    int sum = 0;
#pragma unroll
    for (int j = 0; j < 4; j++) {
        int idx = base + j;
        d[j] = (idx < N) ? (int)deg[idx] : 0;
        sum += d[j];
    }
    s[t] = sum;
    __syncthreads();
    for (int off = 1; off < 256; off <<= 1) {
        int u = (t >= off) ? s[t - off] : 0;
        __syncthreads();
        s[t] += u;
        __syncthreads();
    }
    int run = bsum[blockIdx.x] + s[t] - sum;
#pragma unroll
    for (int j = 0; j < 4; j++) {
        int idx = base + j;
        if (idx < N) {
            row_ptr[idx] = run;
            cursor[idx] = run;
            run += d[j];
        }
    }
}

// ---------------- scatter edges into CSR (by dst); store src and w=dinv[src] ----------------
__global__ void scatter_kernel(const int* ei32, const long long* ei64, const int* flag,
                               const float* dinv, int* cursor, int* csr_src, float* csr_w,
                               int E) {
    int e = blockIdx.x * blockDim.x + threadIdx.x;
    if (e >= E) return;
    int mode = *flag;
    int s, d;
    if (mode) {
        s = (int)ei64[e];
        d = (int)ei64[(size_t)E + e];
    } else {
        s = ei32[e];
        d = ei32[(size_t)E + e];
    }
    int pos = atomicAdd(&cursor[d], 1);
    csr_src[pos] = s;
    csr_w[pos] = dinv[s];
}

// ---------------- fp32-compute GEMM: out_bf16[M x DO] = A[M x 128] @ W[128 x DO] ----------------
// AT = float (fp32 A) or unsigned short (bf16 A). Staged to fp32 in LDS either way.
template <int DO, typename AT>
__global__ __launch_bounds__(256, 2) void gemm_kernel(const AT* __restrict__ A,
                                                      const float* __restrict__ W,
                                                      unsigned short* __restrict__ out, int M) {
    constexpr int CG  = DO / 4;    // col groups of 4
    constexpr int TYN = 256 / CG;  // row groups
    constexpr int RM  = 64 / TYN;  // rows per thread
    __shared__ float As[64 * 64];
    __shared__ float Bs[64 * DO];
    const int tid = threadIdx.x;
    const int row0 = blockIdx.x * 64;
    const int tx = tid % CG, ty = tid / CG;

    float acc[RM][4];
#pragma unroll
    for (int r = 0; r < RM; r++) acc[r][0] = acc[r][1] = acc[r][2] = acc[r][3] = 0.f;

    for (int k0 = 0; k0 < 128; k0 += 64) {
        for (int idx = tid; idx < 64 * 16; idx += 256) {
            int r = idx >> 4, cc = idx & 15;
            int row = row0 + r;
            float4 v = make_float4(0.f, 0.f, 0.f, 0.f);
            if (row < M) {
                if constexpr (sizeof(AT) == 4) {
                    v = ((const float4*)A)[(size_t)row * 32 + (k0 >> 2) + cc];
                } else {
                    ushort4 u = ((const ushort4*)A)[(size_t)row * 32 + (k0 >> 2) + cc];
                    v = make_float4(bf2f(u.x), bf2f(u.y), bf2f(u.z), bf2f(u.w));
                }
            }
            ((float4*)As)[idx] = v;
        }
        for (int idx = tid; idx < 64 * CG; idx += 256) {
            int r = idx / CG, cc = idx % CG;
            ((float4*)Bs)[idx] = ((const float4*)W)[(size_t)(k0 + r) * CG + cc];
        }
        __syncthreads();
#pragma unroll 8
        for (int k = 0; k < 64; k++) {
            float4 b = ((const float4*)Bs)[k * CG + tx];
#pragma unroll
            for (int r = 0; r < RM; r++) {
                float a = As[(ty * RM + r) * 64 + k];
                acc[r][0] = fmaf(a, b.x, acc[r][0]);
                acc[r][1] = fmaf(a, b.y, acc[r][1]);
                acc[r][2] = fmaf(a, b.z, acc[r][2]);
                acc[r][3] = fmaf(a, b.w, acc[r][3]);
            }
        }
        __syncthreads();
    }
#pragma unroll
    for (int r = 0; r < RM; r++) {
        int row = row0 + ty * RM + r;
        if (row < M) {
            ushort4 v;
            v.x = f2bf(acc[r][0]);
            v.y = f2bf(acc[r][1]);
            v.z = f2bf(acc[r][2]);
            v.w = f2bf(acc[r][3]);
            ((ushort4*)out)[(size_t)row * CG + tx] = v;
        }
    }
}

// ---------------- CSR aggregation v2: wave-per-node, bf16 gather, fp32 accumulate ----------
// out[i] = dinv[i]*(dinv[i]*h[i] + sum_e w_e*h[src_e]) + b
// D=128: lane owns cols {2*lane, 2*lane+1} via one uint load per edge.
// D=64 : lane owns col lane via one ushort load per edge.
// OT = unsigned short (bf16 out) or float (fp32 out).
template <int D, bool RELU, typename OT>
__global__ __launch_bounds__(256) void agg_kernel(const unsigned short* __restrict__ h,
                                                  const int* __restrict__ csr_src,
                                                  const float* __restrict__ csr_w,
                                                  const int* __restrict__ row_ptr,
                                                  const float* __restrict__ dinv,
                                                  const float* __restrict__ bias,
                                                  OT* __restrict__ out, int N) {
    const int wid = threadIdx.x >> 6;
    const int lane = threadIdx.x & 63;
    const int i = blockIdx.x * 4 + wid;
    if (i >= N) return;
    const float di = dinv[i];
    const int start = row_ptr[i], end = row_ptr[i + 1];

    if constexpr (D == 128) {
        const unsigned* hu = (const unsigned*)h;
        unsigned sv = hu[(size_t)i * 64 + lane];
        float a0 = di * bflo(sv), b0 = di * bfhi(sv);  // self loop
        float a1 = 0.f, b1 = 0.f;
        int j = start;
        for (; j + 4 <= end; j += 4) {
            int s0 = csr_src[j], s1 = csr_src[j + 1], s2 = csr_src[j + 2], s3 = csr_src[j + 3];
            float w0 = csr_w[j], w1 = csr_w[j + 1], w2 = csr_w[j + 2], w3 = csr_w[j + 3];
            unsigned v0 = hu[(size_t)s0 * 64 + lane];
            unsigned v1 = hu[(size_t)s1 * 64 + lane];
            unsigned v2 = hu[(size_t)s2 * 64 + lane];
            unsigned v3 = hu[(size_t)s3 * 64 + lane];
            a0 = fmaf(w0, bflo(v0), a0);
            b0 = fmaf(w0, bfhi(v0), b0);
            a1 = fmaf(w1, bflo(v1), a1);
            b1 = fmaf(w1, bfhi(v1), b1);
            a0 = fmaf(w2, bflo(v2), a0);
            b0 = fmaf(w2, bfhi(v2), b0);
            a1 = fmaf(w3, bflo(v3), a1);
            b1 = fmaf(w3, bfhi(v3), b1);
        }
        for (; j < end; ++j) {
            int s0 = csr_src[j];
            float w0 = csr_w[j];
            unsigned v0 = hu[(size_t)s0 * 64 + lane];
            a0 = fmaf(w0, bflo(v0), a0);
            b0 = fmaf(w0, bfhi(v0), b0);
        }
        float rx = di * (a0 + a1) + bias[2 * lane];
        float ry = di * (b0 + b1) + bias[2 * lane + 1];
        if (RELU) {
            rx = fmaxf(rx, 0.f);
            ry = fmaxf(ry, 0.f);
        }
        if constexpr (sizeof(OT) == 2) {
            unsigned pv = (unsigned)f2bf(rx) | ((unsigned)f2bf(ry) << 16);
            ((unsigned*)out)[(size_t)i * 64 + lane] = pv;
        } else {
            float2 pv = make_float2(rx, ry);
            ((float2*)out)[(size_t)i * 64 + lane] = pv;
        }
    } else {  // D == 64
        float a0 = di * bf2f(h[(size_t)i * 64 + lane]);  // self loop
        float a1 = 0.f;
        int j = start;
        for (; j + 4 <= end; j += 4) {
            int s0 = csr_src[j], s1 = csr_src[j + 1], s2 = csr_src[j + 2], s3 = csr_src[j + 3];
            float w0 = csr_w[j], w1 = csr_w[j + 1], w2 = csr_w[j + 2], w3 = csr_w[j + 3];
            float v0 = bf2f(h[(size_t)s0 * 64 + lane]);
            float v1 = bf2f(h[(size_t)s1 * 64 + lane]);
            float v2 = bf2f(h[(size_t)s2 * 64 + lane]);
            float v3 = bf2f(h[(size_t)s3 * 64 + lane]);
            a0 = fmaf(w0, v0, a0);
            a1 = fmaf(w1, v1, a1);
            a0 = fmaf(w2, v2, a0);
            a1 = fmaf(w3, v3, a1);
        }
        for (; j < end; ++j) {
            a0 = fmaf(csr_w[j], bf2f(h[(size_t)csr_src[j] * 64 + lane]), a0);
        }
        float r = di * (a0 + a1) + bias[lane];
        if (RELU) r = fmaxf(r, 0.f);
        if constexpr (sizeof(OT) == 2) {
            out[(size_t)i * 64 + lane] = (OT)f2bf(r);
        } else {
            out[(size_t)i * 64 + lane] = r;
        }
    }
}

extern "C" void kernel_launch(void* const* d_in, const int* in_sizes, int n_in,
                              void* d_out, int out_size, void* d_ws, size_t ws_size,
                              hipStream_t stream) {
    const float* x  = (const float*)d_in[0];
    const void*  ei = d_in[1];
    const float* W1 = (const float*)d_in[2];
    const float* b1 = (const float*)d_in[3];
    const float* W2 = (const float*)d_in[4];
    const float* b2 = (const float*)d_in[5];
    float* out = (float*)d_out;

    const int N = in_sizes[0] / DIN;
    const int E = in_sizes[1] / 2;

    char* ws = (char*)d_ws;
    size_t off = 0;
    auto alloc = [&](size_t bytes) -> void* {
        void* p = ws + off;
        off += (bytes + 255) & ~(size_t)255;
        return p;
    };
    unsigned*       deg  = (unsigned*)alloc((size_t)N * 4);
    float*          dinv = (float*)alloc((size_t)N * 4);
    int*            rowp = (int*)alloc((size_t)(N + 1) * 4);
    int*            curs = (int*)alloc((size_t)N * 4);
    int*            flag = (int*)alloc(256);
    int*            bsum = (int*)alloc(1024 * 4);
    int*            csrs = (int*)alloc((size_t)E * 4);
    float*          csrw = (float*)alloc((size_t)E * 4);
    unsigned short* h1   = (unsigned short*)alloc((size_t)N * DHID * 2);  // bf16
    unsigned short* o1   = (unsigned short*)alloc((size_t)N * DHID * 2);  // bf16
    unsigned short* h2   = h1;  // h1 dead after agg1; reuse (bf16, smaller)

    const int nb = (N + 1023) / 1024;

    hipMemsetAsync(deg, 0, (size_t)N * 4, stream);
    detect_i64_kernel<<<1, 64, 0, stream>>>((const unsigned*)ei, flag);
    deg_count_kernel<<<(E + 255) / 256, 256, 0, stream>>>((const int*)ei, (const long long*)ei,
                                                          flag, deg, E);
    dinv_kernel<<<(N + 255) / 256, 256, 0, stream>>>(deg, dinv, N);
    scan_blocksum_kernel<<<nb, 256, 0, stream>>>(deg, bsum, N);
    scan_bsum_kernel<<<1, 256, 0, stream>>>(bsum, rowp, nb, N);
    scan_write_kernel<<<nb, 256, 0, stream>>>(deg, bsum, rowp, curs, N);
    scatter_kernel<<<(E + 255) / 256, 256, 0, stream>>>((const int*)ei, (const long long*)ei,
                                                        flag, dinv, curs, csrs, csrw, E);
    gemm_kernel<DHID, float><<<(N + 63) / 64, 256, 0, stream>>>(x, W1, h1, N);
    agg_kernel<DHID, true, unsigned short><<<(N + 3) / 4, 256, 0, stream>>>(h1, csrs, csrw, rowp,
                                                                            dinv, b1, o1, N);
    gemm_kernel<DOUT2, unsigned short><<<(N + 63) / 64, 256, 0, stream>>>(o1, W2, h2, N);
    agg_kernel<DOUT2, false, float><<<(N + 3) / 4, 256, 0, stream>>>(h2, csrs, csrw, rowp, dinv,
                                                                     b2, out, N);
}

// Round 5
// 243.170 us; speedup vs baseline: 1.1292x; 1.1292x over previous
//
#include <hip/hip_runtime.h>
#include <hip/hip_fp16.h>
#include <stdint.h>

#define DIN 128
#define DHID 128
#define DOUT2 64

// fp32 -> bf16 (round to nearest even), as raw ushort
__device__ __forceinline__ unsigned short f2bf(float f) {
    unsigned u = __float_as_uint(f);
    u += 0x7fffu + ((u >> 16) & 1u);
    return (unsigned short)(u >> 16);
}
__device__ __forceinline__ float bf2f(unsigned short b) {
    return __uint_as_float(((unsigned)b) << 16);
}
__device__ __forceinline__ float bflo(unsigned v) { return __uint_as_float(v << 16); }
__device__ __forceinline__ float bfhi(unsigned v) { return __uint_as_float(v & 0xffff0000u); }
__device__ __forceinline__ unsigned short f2h(float f) {
    return __half_as_ushort(__float2half_rn(f));
}
__device__ __forceinline__ float h2f(unsigned bits) {
    return __half2float(__ushort_as_half((unsigned short)bits));
}

// ---------------- dtype detector (int32 vs int64 edge_index) ----------------
__global__ void detect_i64_kernel(const unsigned* ei, int* flag) {
    int t = threadIdx.x;
    unsigned hi = ei[2 * t + 1];
    unsigned long long vote = __ballot(hi == 0u);
    if (t == 0) *flag = (vote == ~0ull) ? 1 : 0;
}

// ---------------- GEMM block worker (fp32 compute, bf16 out) ----------------
template <int DO, typename AT>
__device__ __forceinline__ void gemm_block(const AT* __restrict__ A, const float* __restrict__ W,
                                           unsigned short* __restrict__ out, int M, int bx,
                                           float* As, float* Bs) {
    constexpr int CG  = DO / 4;    // col groups of 4
    constexpr int TYN = 256 / CG;  // row groups
    constexpr int RM  = 64 / TYN;  // rows per thread
    const int tid = threadIdx.x;
    const int row0 = bx * 64;
    const int tx = tid % CG, ty = tid / CG;

    float acc[RM][4];
#pragma unroll
    for (int r = 0; r < RM; r++) acc[r][0] = acc[r][1] = acc[r][2] = acc[r][3] = 0.f;

    for (int k0 = 0; k0 < 128; k0 += 64) {
        for (int idx = tid; idx < 64 * 16; idx += 256) {
            int r = idx >> 4, cc = idx & 15;
            int row = row0 + r;
            float4 v = make_float4(0.f, 0.f, 0.f, 0.f);
            if (row < M) {
                if constexpr (sizeof(AT) == 4) {
                    v = ((const float4*)A)[(size_t)row * 32 + (k0 >> 2) + cc];
                } else {
                    ushort4 u = ((const ushort4*)A)[(size_t)row * 32 + (k0 >> 2) + cc];
                    v = make_float4(bf2f(u.x), bf2f(u.y), bf2f(u.z), bf2f(u.w));
                }
            }
            ((float4*)As)[idx] = v;
        }
        for (int idx = tid; idx < 64 * CG; idx += 256) {
            int r = idx / CG, cc = idx % CG;
            ((float4*)Bs)[idx] = ((const float4*)W)[(size_t)(k0 + r) * CG + cc];
        }
        __syncthreads();
#pragma unroll 8
        for (int k = 0; k < 64; k++) {
            float4 b = ((const float4*)Bs)[k * CG + tx];
#pragma unroll
            for (int r = 0; r < RM; r++) {
                float a = As[(ty * RM + r) * 64 + k];
                acc[r][0] = fmaf(a, b.x, acc[r][0]);
                acc[r][1] = fmaf(a, b.y, acc[r][1]);
                acc[r][2] = fmaf(a, b.z, acc[r][2]);
                acc[r][3] = fmaf(a, b.w, acc[r][3]);
            }
        }
        __syncthreads();
    }
#pragma unroll
    for (int r = 0; r < RM; r++) {
        int row = row0 + ty * RM + r;
        if (row < M) {
            ushort4 v;
            v.x = f2bf(acc[r][0]);
            v.y = f2bf(acc[r][1]);
            v.z = f2bf(acc[r][2]);
            v.w = f2bf(acc[r][3]);
            ((ushort4*)out)[(size_t)row * CG + tx] = v;
        }
    }
}

// ---------------- fused: gemm1 (blocks < gemmBlocks) || deg_count (rest) ----------------
__global__ __launch_bounds__(256, 2) void fused_gemm_deg_kernel(
    const float* __restrict__ A, const float* __restrict__ W, unsigned short* __restrict__ out,
    int M, int gemmBlocks, const int* ei32, const long long* ei64, const int* flag,
    unsigned* deg, int E) {
    __shared__ float As[64 * 64];
    __shared__ float Bs[64 * DHID];
    if ((int)blockIdx.x < gemmBlocks) {
        gemm_block<DHID, float>(A, W, out, M, blockIdx.x, As, Bs);
    } else {
        int e = (blockIdx.x - gemmBlocks) * 256 + threadIdx.x;
        if (e < E) {
            int mode = *flag;
            int d = mode ? (int)ei64[(size_t)E + e] : ei32[(size_t)E + e];
            atomicAdd(&deg[d], 1u);
        }
    }
}

// ---------------- standalone GEMM (layer 2) ----------------
template <int DO, typename AT>
__global__ __launch_bounds__(256, 2) void gemm_kernel(const AT* __restrict__ A,
                                                      const float* __restrict__ W,
                                                      unsigned short* __restrict__ out, int M) {
    __shared__ float As[64 * 64];
    __shared__ float Bs[64 * DO];
    gemm_block<DO, AT>(A, W, out, M, blockIdx.x, As, Bs);
}

// ---------------- scan pass 1 + dinv: per-block (1024 elems) sums ----------------
__global__ __launch_bounds__(256) void scan_blocksum_kernel(const unsigned* deg, int* bsum,
                                                            float* dinv, int N) {
    __shared__ int s[256];
    int t = threadIdx.x;
    int base = blockIdx.x * 1024 + t * 4;
    int sum = 0;
    if (base + 3 < N) {
        int4 v = *(const int4*)((const int*)deg + base);
        sum = v.x + v.y + v.z + v.w;
        float4 dv;
        dv.x = rsqrtf((float)(v.x + 1));
        dv.y = rsqrtf((float)(v.y + 1));
        dv.z = rsqrtf((float)(v.z + 1));
        dv.w = rsqrtf((float)(v.w + 1));
        *(float4*)(dinv + base) = dv;
    } else {
        for (int j = 0; j < 4; j++)
            if (base + j < N) {
                int d = (int)deg[base + j];
                sum += d;
                dinv[base + j] = rsqrtf((float)(d + 1));
            }
    }
    s[t] = sum;
    __syncthreads();
    for (int off = 128; off > 0; off >>= 1) {
        if (t < off) s[t] += s[t + off];
        __syncthreads();
    }
    if (t == 0) bsum[blockIdx.x] = s[0];
}

__global__ __launch_bounds__(256) void scan_bsum_kernel(int* bsum, int* row_ptr, int nb, int N) {
    __shared__ int s[256];
    int t = threadIdx.x;
    int v = (t < nb) ? bsum[t] : 0;
    s[t] = v;
    __syncthreads();
    for (int off = 1; off < 256; off <<= 1) {
        int u = (t >= off) ? s[t - off] : 0;
        __syncthreads();
        s[t] += u;
        __syncthreads();
    }
    if (t < nb) bsum[t] = s[t] - v;  // exclusive
    if (t == 255) row_ptr[N] = s[255];
}

__global__ __launch_bounds__(256) void scan_write_kernel(const unsigned* deg, const int* bsum,
                                                         int* row_ptr, int* cursor, int N) {
    __shared__ int s[256];
    int t = threadIdx.x;
    int base = blockIdx.x * 1024 + t * 4;
    int d[4];
    int sum = 0;
#pragma unroll
    for (int j = 0; j < 4; j++) {
        int idx = base + j;
        d[j] = (idx < N) ? (int)deg[idx] : 0;
        sum += d[j];
    }
    s[t] = sum;
    __syncthreads();
    for (int off = 1; off < 256; off <<= 1) {
        int u = (t >= off) ? s[t - off] : 0;
        __syncthreads();
        s[t] += u;
        __syncthreads();
    }
    int run = bsum[blockIdx.x] + s[t] - sum;
#pragma unroll
    for (int j = 0; j < 4; j++) {
        int idx = base + j;
        if (idx < N) {
            row_ptr[idx] = run;
            cursor[idx] = run;
            run += d[j];
        }
    }
}

// ---------------- scatter edges into packed CSR ----------------
// pack32: {u16 src | f16 dinv[src]}  (valid when N <= 65535)
__global__ void scatter_pack32_kernel(const int* ei32, const long long* ei64, const int* flag,
                                      const float* dinv, int* cursor, unsigned* csr, int E) {
    int e = blockIdx.x * blockDim.x + threadIdx.x;
    if (e >= E) return;
    int mode = *flag;
    int s, d;
    if (mode) {
        s = (int)ei64[e];
        d = (int)ei64[(size_t)E + e];
    } else {
        s = ei32[e];
        d = ei32[(size_t)E + e];
    }
    int pos = atomicAdd(&cursor[d], 1);
    csr[pos] = (unsigned)s | ((unsigned)f2h(dinv[s]) << 16);
}

// pack64: {u32 src | f32 w} fallback for large N
__global__ void scatter_pack64_kernel(const int* ei32, const long long* ei64, const int* flag,
                                      const float* dinv, int* cursor, unsigned long long* csr,
                                      int E) {
    int e = blockIdx.x * blockDim.x + threadIdx.x;
    if (e >= E) return;
    int mode = *flag;
    int s, d;
    if (mode) {
        s = (int)ei64[e];
        d = (int)ei64[(size_t)E + e];
    } else {
        s = ei32[e];
        d = ei32[(size_t)E + e];
    }
    int pos = atomicAdd(&cursor[d], 1);
    csr[pos] = (unsigned long long)(unsigned)s |
               ((unsigned long long)__float_as_uint(dinv[s]) << 32);
}

__device__ __forceinline__ void unpack(unsigned p, int& s, float& w) {
    s = (int)(p & 0xffffu);
    w = h2f(p >> 16);
}
__device__ __forceinline__ void unpack(unsigned long long p, int& s, float& w) {
    s = (int)(unsigned)(p & 0xffffffffu);
    w = __uint_as_float((unsigned)(p >> 32));
}

// ---------------- CSR aggregation: wave-per-node, bf16 gather, fp32 accumulate ----------
// out[i] = dinv[i]*(dinv[i]*h[i] + sum_e w_e*h[src_e]) + b
template <int D, bool RELU, typename OT, typename CT>
__global__ __launch_bounds__(256) void agg_kernel(const unsigned short* __restrict__ h,
                                                  const CT* __restrict__ csr,
                                                  const int* __restrict__ row_ptr,
                                                  const float* __restrict__ dinv,
                                                  const float* __restrict__ bias,
                                                  OT* __restrict__ out, int N) {
    const int wid = threadIdx.x >> 6;
    const int lane = threadIdx.x & 63;
    const int i = blockIdx.x * 4 + wid;
    if (i >= N) return;
    const float di = dinv[i];
    const int start = row_ptr[i], end = row_ptr[i + 1];

    if constexpr (D == 128) {
        const unsigned* hu = (const unsigned*)h;
        unsigned sv = hu[(size_t)i * 64 + lane];
        float a0 = di * bflo(sv), b0 = di * bfhi(sv);  // self loop
        float a1 = 0.f, b1 = 0.f;
        int j = start;
        for (; j + 4 <= end; j += 4) {
            CT p0 = csr[j], p1 = csr[j + 1], p2 = csr[j + 2], p3 = csr[j + 3];
            int s0, s1, s2, s3;
            float w0, w1, w2, w3;
            unpack(p0, s0, w0);
            unpack(p1, s1, w1);
            unpack(p2, s2, w2);
            unpack(p3, s3, w3);
            unsigned v0 = hu[(size_t)s0 * 64 + lane];
            unsigned v1 = hu[(size_t)s1 * 64 + lane];
            unsigned v2 = hu[(size_t)s2 * 64 + lane];
            unsigned v3 = hu[(size_t)s3 * 64 + lane];
            a0 = fmaf(w0, bflo(v0), a0);
            b0 = fmaf(w0, bfhi(v0), b0);
            a1 = fmaf(w1, bflo(v1), a1);
            b1 = fmaf(w1, bfhi(v1), b1);
            a0 = fmaf(w2, bflo(v2), a0);
            b0 = fmaf(w2, bfhi(v2), b0);
            a1 = fmaf(w3, bflo(v3), a1);
            b1 = fmaf(w3, bfhi(v3), b1);
        }
        for (; j < end; ++j) {
            int s0;
            float w0;
            unpack(csr[j], s0, w0);
            unsigned v0 = hu[(size_t)s0 * 64 + lane];
            a0 = fmaf(w0, bflo(v0), a0);
            b0 = fmaf(w0, bfhi(v0), b0);
        }
        float2 bv = ((const float2*)bias)[lane];
        float rx = di * (a0 + a1) + bv.x;
        float ry = di * (b0 + b1) + bv.y;
        if (RELU) {
            rx = fmaxf(rx, 0.f);
            ry = fmaxf(ry, 0.f);
        }
        if constexpr (sizeof(OT) == 2) {
            unsigned pv = (unsigned)f2bf(rx) | ((unsigned)f2bf(ry) << 16);
            ((unsigned*)out)[(size_t)i * 64 + lane] = pv;
        } else {
            ((float2*)out)[(size_t)i * 64 + lane] = make_float2(rx, ry);
        }
    } else {  // D == 64
        float a0 = di * bf2f(h[(size_t)i * 64 + lane]);  // self loop
        float a1 = 0.f;
        int j = start;
        for (; j + 4 <= end; j += 4) {
            CT p0 = csr[j], p1 = csr[j + 1], p2 = csr[j + 2], p3 = csr[j + 3];
            int s0, s1, s2, s3;
            float w0, w1, w2, w3;
            unpack(p0, s0, w0);
            unpack(p1, s1, w1);
            unpack(p2, s2, w2);
            unpack(p3, s3, w3);
            float v0 = bf2f(h[(size_t)s0 * 64 + lane]);
            float v1 = bf2f(h[(size_t)s1 * 64 + lane]);
            float v2 = bf2f(h[(size_t)s2 * 64 + lane]);
            float v3 = bf2f(h[(size_t)s3 * 64 + lane]);
            a0 = fmaf(w0, v0, a0);
            a1 = fmaf(w1, v1, a1);
            a0 = fmaf(w2, v2, a0);
            a1 = fmaf(w3, v3, a1);
        }
        for (; j < end; ++j) {
            int s0;
            float w0;
            unpack(csr[j], s0, w0);
            a0 = fmaf(w0, bf2f(h[(size_t)s0 * 64 + lane]), a0);
        }
        float r = di * (a0 + a1) + bias[lane];
        if (RELU) r = fmaxf(r, 0.f);
        if constexpr (sizeof(OT) == 2) {
            out[(size_t)i * 64 + lane] = (OT)f2bf(r);
        } else {
            out[(size_t)i * 64 + lane] = r;
        }
    }
}

extern "C" void kernel_launch(void* const* d_in, const int* in_sizes, int n_in,
                              void* d_out, int out_size, void* d_ws, size_t ws_size,
                              hipStream_t stream) {
    const float* x  = (const float*)d_in[0];
    const void*  ei = d_in[1];
    const float* W1 = (const float*)d_in[2];
    const float* b1 = (const float*)d_in[3];
    const float* W2 = (const float*)d_in[4];
    const float* b2 = (const float*)d_in[5];
    float* out = (float*)d_out;

    const int N = in_sizes[0] / DIN;
    const int E = in_sizes[1] / 2;

    char* ws = (char*)d_ws;
    size_t off = 0;
    auto alloc = [&](size_t bytes) -> void* {
        void* p = ws + off;
        off += (bytes + 255) & ~(size_t)255;
        return p;
    };
    unsigned*       deg  = (unsigned*)alloc((size_t)N * 4);
    float*          dinv = (float*)alloc((size_t)N * 4);
    int*            rowp = (int*)alloc((size_t)(N + 1) * 4);
    int*            curs = (int*)alloc((size_t)N * 4);
    int*            flag = (int*)alloc(256);
    int*            bsum = (int*)alloc(1024 * 4);
    void*           csr  = alloc((size_t)E * 8);  // 4B used when N<=65535
    unsigned short* h1   = (unsigned short*)alloc((size_t)N * DHID * 2);  // bf16
    unsigned short* o1   = (unsigned short*)alloc((size_t)N * DHID * 2);  // bf16
    unsigned short* h2   = h1;  // h1 dead after agg1; reuse

    const int nb = (N + 1023) / 1024;
    const int gemmBlocks = (N + 63) / 64;
    const int degBlocks = (E + 255) / 256;

    hipMemsetAsync(deg, 0, (size_t)N * 4, stream);
    detect_i64_kernel<<<1, 64, 0, stream>>>((const unsigned*)ei, flag);
    // gemm1 (x @ W1 -> h1 bf16)  ||  deg histogram
    fused_gemm_deg_kernel<<<gemmBlocks + degBlocks, 256, 0, stream>>>(
        x, W1, h1, N, gemmBlocks, (const int*)ei, (const long long*)ei, flag, deg, E);
    scan_blocksum_kernel<<<nb, 256, 0, stream>>>(deg, bsum, dinv, N);
    scan_bsum_kernel<<<1, 256, 0, stream>>>(bsum, rowp, nb, N);
    scan_write_kernel<<<nb, 256, 0, stream>>>(deg, bsum, rowp, curs, N);

    if (N <= 65535) {
        unsigned* csr32 = (unsigned*)csr;
        scatter_pack32_kernel<<<degBlocks, 256, 0, stream>>>(
            (const int*)ei, (const long long*)ei, flag, dinv, curs, csr32, E);
        agg_kernel<DHID, true, unsigned short, unsigned><<<(N + 3) / 4, 256, 0, stream>>>(
            h1, csr32, rowp, dinv, b1, o1, N);
        gemm_kernel<DOUT2, unsigned short><<<gemmBlocks, 256, 0, stream>>>(o1, W2, h2, N);
        agg_kernel<DOUT2, false, float, unsigned><<<(N + 3) / 4, 256, 0, stream>>>(
            h2, csr32, rowp, dinv, b2, out, N);
    } else {
        unsigned long long* csr64 = (unsigned long long*)csr;
        scatter_pack64_kernel<<<degBlocks, 256, 0, stream>>>(
            (const int*)ei, (const long long*)ei, flag, dinv, curs, csr64, E);
        agg_kernel<DHID, true, unsigned short, unsigned long long><<<(N + 3) / 4, 256, 0,
                                                                     stream>>>(h1, csr64, rowp,
                                                                               dinv, b1, o1, N);
        gemm_kernel<DOUT2, unsigned short><<<gemmBlocks, 256, 0, stream>>>(o1, W2, h2, N);
        agg_kernel<DOUT2, false, float, unsigned long long><<<(N + 3) / 4, 256, 0, stream>>>(
            h2, csr64, rowp, dinv, b2, out, N);
    }
}